// Round 6
// baseline (1461.355 us; speedup 1.0000x reference)
//
#include <hip/hip_runtime.h>
#include <hip/hip_bf16.h>
#include <cmath>

// SeqAttention: B=16, S=2048, D=1024, E2=4096.
// R6: register-fragment software pipelining on the 256x256 8-phase GEMM.
//  Phase p issues the ds_reads for phase p+1 (double-banked afr/bfr), so LDS
//  latency hides under phase p's MFMA+barriers instead of sitting exposed
//  between barrier-release and MFMA. lgkmcnt(N) with N = reads just issued
//  (DS returns in-order -> previous set complete). vmcnt(6) at every even
//  phase end (ledger: at p-even end of iter i, issued halves = 8i+7+p;
//  outstanding <=3 guarantees exactly the halves the next phase's
//  read-ahead consumes; stage map unchanged from R5).
//  Banks: afr[QM parity], bfr[K-half parity] -- all indices compile-time.

typedef __bf16 bf16;
typedef __attribute__((ext_vector_type(8))) __bf16 bf16x8;
typedef __attribute__((ext_vector_type(4))) __bf16 bf16x4;
typedef __attribute__((ext_vector_type(4))) float f32x4;

static constexpr int kB  = 16;
static constexpr int kS  = 2048;
static constexpr int kD  = 1024;
static constexpr int kE2 = 4096;
static constexpr int kCB = 8;      // batches per attention chunk (scores = 64MB)
static constexpr int kFR = 16384;  // rows per FFN super-chunk (h = 128MB)

// async global->LDS, 16 bytes per lane; LDS dest wave-uniform base + lane*16.
__device__ __forceinline__ void gload_lds16(const bf16* g, bf16* l) {
    __builtin_amdgcn_global_load_lds(
        (const __attribute__((address_space(1))) void*)g,
        (__attribute__((address_space(3))) void*)l,
        16, 0, 0);
}

// ---------------- fp32 -> bf16 elementwise (4 elems/thread) ----------------
__global__ __launch_bounds__(256) void cvt_bf16_kernel(const float* __restrict__ in,
                                                       bf16* __restrict__ out) {
    size_t i = ((size_t)blockIdx.x * 256 + threadIdx.x) * 4;
    float4 v = *(const float4*)(in + i);
    bf16x4 o;
    o.x = (bf16)v.x; o.y = (bf16)v.y; o.z = (bf16)v.z; o.w = (bf16)v.w;
    *(bf16x4*)(out + i) = o;
}

// ---------------- tiled transpose + convert: out[c][r] = bf16(in[r][c]) ----
__global__ void transpose_cvt_kernel(const float* __restrict__ in, bf16* __restrict__ out,
                                     int R, int C, long long sIn, long long sOut) {
    __shared__ float tile[32][33];
    in  += (size_t)blockIdx.z * sIn;
    out += (size_t)blockIdx.z * sOut;
    const int c0 = blockIdx.x * 32, r0 = blockIdx.y * 32;
    const int tx = threadIdx.x, ty = threadIdx.y;
#pragma unroll
    for (int k = 0; k < 32; k += 8)
        tile[ty + k][tx] = in[(size_t)(r0 + ty + k) * C + (c0 + tx)];
    __syncthreads();
#pragma unroll
    for (int k = 0; k < 32; k += 8)
        out[(size_t)(c0 + ty + k) * R + (r0 + tx)] = (bf16)tile[tx][ty + k];
}

// ---------------- GEMM: C(MxN) = A(MxK) . B^T, B given as (NxK) -----------
// 256x256 tile, BK=64 as two 32-K halves. 8 waves 2x4; per-wave 128x64 out.
// LDS [buf][mat][khalf][256*32] = 128 KiB. Chunk XOR-swizzle (R3-verified, 0
// conflicts): stage source chunk (lane&3)^((lane>>3)&3), read chunk
// quad^((l15>>1)&3). Stage map (iter i, phases 0..7 stage halves 8i+6..8i+13):
//   p0: t=2i+1 A-kh1 b1   p1: t=2i+1 B-kh1 b1
//   p2: t=2i+2 A-kh0 b0   p3: t=2i+2 B-kh0 b0
//   p4: t=2i+2 A-kh1 b0   p5: t=2i+2 B-kh1 b0
//   p6: t=2i+3 A-kh0 b1   p7: t=2i+3 B-kh0 b1
// Read-ahead ledger (vmcnt counts LOADS, 2/half; vmcnt(6) = 3 halves out):
//   p0-end issued 8i+7 halves -> landed idx<=8i+3: covers reads@p1 (8i+2,3)
//   p2-end issued 8i+9 -> idx<=8i+5: covers reads@p3 (8i+4,5)
//   p4-end issued 8i+11 -> idx<=8i+7: covers reads@p5 (8i+6,7)
//   p6-end issued 8i+13 -> idx<=8i+9: covers reads@p7 (8i+8,9 = next p0)
// Reg-bank WAR: phase p MFMA uses afr[QM],bfr[KS]; its read-ahead writes
// afr[1-QM] (even p) or afr[0]+bfr[1-KS] (odd p) -- always disjoint.
// LDS WAR: every stage slot-overwrite is >=1 barrier after that slot's last
// read issue + lgkm retirement (same map as R5, reads shifted 1 phase early;
// checked slot-by-slot: stages at p2..p7 touch buf/khalf slots disjoint from
// the read-ahead outstanding at the intervening barriers).
// MODE 0: Cb = bf16(acc*scale)                (attention scores)
// MODE 1: C  = acc + resF                     (attn_out + residual, fp32)
// MODE 2: Cb = bf16(gelu_exact(acc + bias))   (FFN1 -> h)
// MODE 3: C  = acc + bias + resB              (FFN2 + residual, fp32)
template <int MODE>
__global__ __launch_bounds__(512, 2)
void gemm_bt_kernel(const bf16* __restrict__ A, const bf16* __restrict__ Bm,
                    float* __restrict__ C, bf16* __restrict__ Cb,
                    const float* __restrict__ bias,
                    const float* __restrict__ resF, const bf16* __restrict__ resB,
                    int N, int K,
                    long long sA, long long sB, long long sC, long long sRes,
                    float scale) {
    __shared__ __align__(16) bf16 lds[2][2][2][256 * 32];
    bf16* Lb = &lds[0][0][0][0];
    const int tid  = threadIdx.x;
    const int lane = tid & 63;
    const int wv   = tid >> 6;          // 0..7
    const int wm   = wv >> 2;           // 0..1  M-half
    const int wn   = wv & 3;            // 0..3  N-quarter
    const int quad = lane >> 4, l15 = lane & 15;
    const int quadS = quad ^ ((l15 >> 1) & 3);   // read-side chunk swizzle

    // ---- XCD-aware bijective block swizzle (grids are multiples of 8) ----
    const unsigned gx = gridDim.x, gy = gridDim.y;
    unsigned lin = blockIdx.x + gx * (blockIdx.y + gy * blockIdx.z);
    const unsigned nper = (gx * gy * gridDim.z) >> 3;
    lin = (lin & 7) * nper + (lin >> 3);
    const unsigned bx = lin % gx;
    const unsigned tq = lin / gx;
    const unsigned by = tq % gy;
    const long long z = tq / gy;

    const bf16* Ab = A  + z * sA + (size_t)by * 256 * K;
    const bf16* Bb = Bm + z * sB + (size_t)bx * 256 * K;

    // staging source (per lane): row wv*32 + lane>>2 (+16 for 2nd issue),
    // chunk pre-swizzled in the GLOBAL source (rule #21; LDS write linear).
    const int srow = wv * 32 + (lane >> 2);
    const int scol = ((lane & 3) ^ ((lane >> 3) & 3)) * 8;
    const bf16* gA = Ab + (size_t)srow * K + scol;
    const bf16* gB = Bb + (size_t)srow * K + scol;
    const size_t kk16 = (size_t)16 * K;
    const int NTH = K >> 7;             // K-tile pairs; K in {1024,2048,4096}

    // hoisted frag read bases (elem offsets; per-phase adds are constants)
    const bf16* aP = Lb + ((wm * 128 + l15) * 32 + quadS * 8);
    const bf16* bP = Lb + 16384 + ((wn * 64 + l15) * 32 + quadS * 8);
    bf16* ldsW = Lb + wv * 1024;        // staging dest base (32 rows)

    f32x4 acc[8][4];
#pragma unroll
    for (int i = 0; i < 8; i++)
#pragma unroll
        for (int j = 0; j < 4; j++) {
            f32x4 zv = {0.0f, 0.0f, 0.0f, 0.0f};
            acc[i][j] = zv;
        }

#define STG(GT, SEL, BUF)                                                     \
    do {                                                                      \
        const bf16* g_ = (((SEL) & 1) ? (GT##B) : (GT##A)) + ((SEL) >> 1) * 32; \
        bf16* l_ = ldsW + (BUF) * 32768 + ((SEL) & 1) * 16384 + ((SEL) >> 1) * 8192; \
        gload_lds16(g_, l_);                                                  \
        gload_lds16(g_ + kk16, l_ + 512);                                     \
    } while (0)

#define VMC6 asm volatile("s_waitcnt vmcnt(6)" ::: "memory")
#define VMC0 asm volatile("s_waitcnt vmcnt(0)" ::: "memory")

// read-ahead sets: RDE = B-frags(kh=KS) + A-frags QM0 (8 reads, even target
// phases); RDO = A-frags QM1 (4 reads, odd target phases). Banks: afr[QM],
// bfr[KS] -- literal indices only (rule #20).
#define RDE(BUF, KS)                                                          \
    do {                                                                      \
        _Pragma("unroll")                                                     \
        for (int nf = 0; nf < 4; nf++)                                        \
            bfr[KS][nf] = *(const bf16x8*)(bP + (BUF) * 32768 + (KS) * 8192 + nf * 512); \
        _Pragma("unroll")                                                     \
        for (int mf = 0; mf < 4; mf++)                                        \
            afr[0][mf] = *(const bf16x8*)(aP + (BUF) * 32768 + (KS) * 8192 + mf * 512); \
    } while (0)
#define RDO(BUF, KS)                                                          \
    do {                                                                      \
        _Pragma("unroll")                                                     \
        for (int mf = 0; mf < 4; mf++)                                        \
            afr[1][mf] = *(const bf16x8*)(aP + (BUF) * 32768 + (KS) * 8192 + (4 + mf) * 512); \
    } while (0)

// phase: issue next-phase reads, stage, barrier, wait for THIS phase's regs
// (lgkmcnt(LGN), LGN = reads just issued), MFMA from banks (KS,QM), optional
// vmcnt, barrier.
#define GPHASE(KS, QM, NEXTRD, STG_STMT, VM_STMT, LGN)                        \
    do {                                                                      \
        NEXTRD;                                                               \
        STG_STMT;                                                             \
        asm volatile("" ::: "memory");                                        \
        __builtin_amdgcn_s_barrier();                                         \
        asm volatile("s_waitcnt lgkmcnt(" #LGN ")" ::: "memory");             \
        __builtin_amdgcn_sched_barrier(0);                                    \
        __builtin_amdgcn_s_setprio(1);                                        \
        _Pragma("unroll")                                                     \
        for (int mf = 0; mf < 4; mf++)                                        \
            _Pragma("unroll")                                                 \
            for (int nf = 0; nf < 4; nf++)                                    \
                acc[(QM) * 4 + mf][nf] = __builtin_amdgcn_mfma_f32_16x16x32_bf16( \
                    afr[QM][mf], bfr[KS][nf], acc[(QM) * 4 + mf][nf], 0, 0, 0); \
        __builtin_amdgcn_s_setprio(0);                                        \
        VM_STMT;                                                              \
        __builtin_amdgcn_s_barrier();                                         \
        asm volatile("" ::: "memory");                                        \
    } while (0)

    bf16x8 afr[2][4], bfr[2][4];
    {   // prologue: tile0 all 4 halves (buf0) + tile1 A/B-kh0 (buf1);
        // vmcnt(8) -> h0,h1 landed; barrier; pre-read phase-0 fragments.
        const bf16* t0A = gA;      const bf16* t0B = gB;
        const bf16* t1A = gA + 64; const bf16* t1B = gB + 64;
        STG(t0, 0, 0); STG(t0, 1, 0); STG(t0, 2, 0); STG(t0, 3, 0);
        STG(t1, 0, 1); STG(t1, 1, 1);
        asm volatile("s_waitcnt vmcnt(8)" ::: "memory");
        __builtin_amdgcn_s_barrier();
        asm volatile("" ::: "memory");
        RDE(0, 0);
    }

    for (int i = 0; i < NTH - 1; i++) {
        const bf16* t1A = gA + (size_t)(2 * i + 1) * 64;
        const bf16* t1B = gB + (size_t)(2 * i + 1) * 64;
        const bf16* t2A = t1A + 64;  const bf16* t2B = t1B + 64;
        const bf16* t3A = t1A + 128; const bf16* t3B = t1B + 128;
        GPHASE(0, 0, RDO(0, 0), STG(t1, 2, 1), VMC6,    4);
        GPHASE(0, 1, RDE(0, 1), STG(t1, 3, 1), (void)0, 8);
        GPHASE(1, 0, RDO(0, 1), STG(t2, 0, 0), VMC6,    4);
        GPHASE(1, 1, RDE(1, 0), STG(t2, 1, 0), (void)0, 8);
        GPHASE(0, 0, RDO(1, 0), STG(t2, 2, 0), VMC6,    4);
        GPHASE(0, 1, RDE(1, 1), STG(t2, 3, 0), (void)0, 8);
        GPHASE(1, 0, RDO(1, 1), STG(t3, 0, 1), VMC6,    4);
        GPHASE(1, 1, RDE(0, 0), STG(t3, 1, 1), (void)0, 8);
    }
    {   // peeled last pair: stage final two halves, settle vmcnt(0)@p2.
        const int i = NTH - 1;
        const bf16* t1A = gA + (size_t)(2 * i + 1) * 64;
        const bf16* t1B = gB + (size_t)(2 * i + 1) * 64;
        GPHASE(0, 0, RDO(0, 0), STG(t1, 2, 1), VMC6,    4);
        GPHASE(0, 1, RDE(0, 1), STG(t1, 3, 1), (void)0, 8);
        GPHASE(1, 0, RDO(0, 1), (void)0,       VMC0,    4);
        GPHASE(1, 1, RDE(1, 0), (void)0,       (void)0, 8);
        GPHASE(0, 0, RDO(1, 0), (void)0,       (void)0, 4);
        GPHASE(0, 1, RDE(1, 1), (void)0,       (void)0, 8);
        GPHASE(1, 0, RDO(1, 1), (void)0,       (void)0, 4);
        GPHASE(1, 1, (void)0,   (void)0,       (void)0, 0);
    }
#undef GPHASE
#undef RDE
#undef RDO
#undef STG
#undef VMC6
#undef VMC0

    // epilogue: C/D layout col = l15, row = quad*4 + reg (m89-verified)
    const size_t m0 = (size_t)by * 256 + wm * 128;
    const size_t n0 = (size_t)bx * 256 + wn * 64;
#pragma unroll
    for (int nf = 0; nf < 4; nf++) {
        const size_t col = n0 + nf * 16 + l15;
        const float bcol = (MODE == 2 || MODE == 3) ? bias[col] : 0.0f;
#pragma unroll
        for (int mf = 0; mf < 8; mf++) {
#pragma unroll
            for (int rr = 0; rr < 4; rr++) {
                const size_t row = m0 + mf * 16 + quad * 4 + rr;
                const float v = acc[mf][nf][rr];
                if (MODE == 0) {
                    Cb[z * sC + row * N + col] = (bf16)(v * scale);
                } else if (MODE == 1) {
                    C[z * sC + row * N + col] = v + resF[z * sRes + row * N + col];
                } else if (MODE == 2) {
                    const float t = v + bcol;
                    const float gl = 0.5f * t * (1.0f + erff(t * 0.70710678118654752f));
                    Cb[row * N + col] = (bf16)gl;
                } else {
                    C[row * N + col] = v + bcol + (float)resB[row * N + col];
                }
            }
        }
    }
}

// ---------------- row softmax over T=2048, bf16 in-place -------------------
__global__ __launch_bounds__(256)
void softmax_bf16_kernel(bf16* __restrict__ SP) {
    __shared__ float red[8];
    const size_t row = blockIdx.x;
    bf16* p = SP + row * kS;
    const int tid = threadIdx.x;
    bf16x8 v = *(const bf16x8*)(p + tid * 8);
    float f[8];
#pragma unroll
    for (int i = 0; i < 8; i++) f[i] = (float)v[i];
    float m = f[0];
#pragma unroll
    for (int i = 1; i < 8; i++) m = fmaxf(m, f[i]);
#pragma unroll
    for (int o = 32; o > 0; o >>= 1) m = fmaxf(m, __shfl_down(m, o, 64));
    if ((tid & 63) == 0) red[tid >> 6] = m;
    __syncthreads();
    m = fmaxf(fmaxf(red[0], red[1]), fmaxf(red[2], red[3]));
    float e[8], s = 0.0f;
#pragma unroll
    for (int i = 0; i < 8; i++) { e[i] = __expf(f[i] - m); s += e[i]; }
#pragma unroll
    for (int o = 32; o > 0; o >>= 1) s += __shfl_down(s, o, 64);
    __syncthreads();
    if ((tid & 63) == 0) red[4 + (tid >> 6)] = s;
    __syncthreads();
    s = red[4] + red[5] + red[6] + red[7];
    const float inv = 1.0f / s;
    bf16x8 o;
#pragma unroll
    for (int i = 0; i < 8; i++) o[i] = (bf16)(e[i] * inv);
    *(bf16x8*)(p + tid * 8) = o;
}

// ---------------- row LayerNorm over D=1024 (fp32 in), fp32/bf16 out -------
__global__ __launch_bounds__(256)
void layernorm_kernel(const float* __restrict__ in, const float* __restrict__ g,
                      const float* __restrict__ be, float* __restrict__ outF,
                      bf16* __restrict__ outB) {
    __shared__ float red[8];
    const size_t row = blockIdx.x;
    const float* src = in + row * kD;
    const int tid = threadIdx.x;
    float4 v = *(const float4*)(src + tid * 4);
    float s = v.x + v.y + v.z + v.w;
#pragma unroll
    for (int o = 32; o > 0; o >>= 1) s += __shfl_down(s, o, 64);
    if ((tid & 63) == 0) red[tid >> 6] = s;
    __syncthreads();
    const float mu = (red[0] + red[1] + red[2] + red[3]) * (1.0f / kD);
    const float d0 = v.x - mu, d1 = v.y - mu, d2 = v.z - mu, d3 = v.w - mu;
    float ss = d0 * d0 + d1 * d1 + d2 * d2 + d3 * d3;
#pragma unroll
    for (int o = 32; o > 0; o >>= 1) ss += __shfl_down(ss, o, 64);
    __syncthreads();
    if ((tid & 63) == 0) red[4 + (tid >> 6)] = ss;
    __syncthreads();
    const float var = (red[4] + red[5] + red[6] + red[7]) * (1.0f / kD);
    const float rstd = rsqrtf(var + 1e-5f);
    float4 gg = *(const float4*)(g + tid * 4);
    float4 bb = *(const float4*)(be + tid * 4);
    float4 o;
    o.x = d0 * rstd * gg.x + bb.x;
    o.y = d1 * rstd * gg.y + bb.y;
    o.z = d2 * rstd * gg.z + bb.z;
    o.w = d3 * rstd * gg.w + bb.w;
    if (outF) *(float4*)(outF + row * kD + tid * 4) = o;
    if (outB) {
        bf16x4 ob;
        ob.x = (bf16)o.x; ob.y = (bf16)o.y; ob.z = (bf16)o.z; ob.w = (bf16)o.w;
        *(bf16x4*)(outB + row * kD + tid * 4) = ob;
    }
}

extern "C" void kernel_launch(void* const* d_in, const int* in_sizes, int n_in,
                              void* d_out, int out_size, void* d_ws, size_t ws_size,
                              hipStream_t stream) {
    const float* lags = (const float*)d_in[0];
    const float* W1   = (const float*)d_in[1];
    const float* b1   = (const float*)d_in[2];
    const float* W2   = (const float*)d_in[3];
    const float* b2   = (const float*)d_in[4];
    const float* g1   = (const float*)d_in[5];
    const float* be1  = (const float*)d_in[6];
    const float* g3   = (const float*)d_in[7];
    const float* be3  = (const float*)d_in[8];
    float* out = (float*)d_out;   // also used as fp32 scratch (x_pre, then y)

    // ---- workspace carve-up: 208 MiB total ----
    // lagsb  bf16 [16][2048][1024]   64 MiB  @0    (QK^T operands; REUSED as xb)
    // W1T    bf16 [4096][1024]        8 MiB  @64M
    // W2T    bf16 [1024][4096]        8 MiB  @72M
    // lagsT  bf16 [16][1024][2048]   64 MiB  @80M  (V^T; DEAD after attention)
    // SP     bf16 [8][2048][2048]    64 MiB  @144M (scores/probs per chunk)
    // h = lagsT..SP = [16384][4096] bf16 = 128 MiB contiguous (FFN phase)
    const size_t REQUIRED = (size_t)(64 + 8 + 8 + 64 + 64) * 1024 * 1024;
    if (ws_size < REQUIRED) return;

    char* w = (char*)d_ws;
    bf16* lagsb = (bf16*)w; w += (size_t)kB * kS * kD * 2;
    bf16* W1T   = (bf16*)w; w += (size_t)kD * kE2 * 2;
    bf16* W2T   = (bf16*)w; w += (size_t)kE2 * kD * 2;
    bf16* lagsT = (bf16*)w; w += (size_t)kB * kD * kS * 2;
    bf16* SP    = (bf16*)w;
    bf16* xb    = lagsb;
    bf16* h     = lagsT;    // spans lagsT + SP (128 MiB)

    const int n = kB * kS * kD;

    // ---- operand prep ----
    cvt_bf16_kernel<<<n / 1024, 256, 0, stream>>>(lags, lagsb);
    transpose_cvt_kernel<<<dim3(kD / 32, kS / 32, kB), dim3(32, 8), 0, stream>>>(
        lags, lagsT, kS, kD, (long long)kS * kD, (long long)kD * kS);
    transpose_cvt_kernel<<<dim3(kE2 / 32, kD / 32, 1), dim3(32, 8), 0, stream>>>(
        W1, W1T, kD, kE2, 0, 0);
    transpose_cvt_kernel<<<dim3(kD / 32, kE2 / 32, 1), dim3(32, 8), 0, stream>>>(
        W2, W2T, kE2, kD, 0, 0);

    // ---- attention, kCB batches at a time ----
    for (int c = 0; c < kB / kCB; c++) {
        const size_t off = (size_t)c * kCB * kS * kD;
        // scores = bf16((lags @ lags^T) / 32)
        gemm_bt_kernel<0><<<dim3(kS / 256, kS / 256, kCB), 512, 0, stream>>>(
            lagsb + off, lagsb + off, nullptr, SP, nullptr, nullptr, nullptr,
            kS, kD, (long long)kS * kD, (long long)kS * kD, (long long)kS * kS, 0, 0.03125f);
        // P = softmax(scores), in place
        softmax_bf16_kernel<<<kCB * kS, 256, 0, stream>>>(SP);
        // x_pre = P @ V + lags   -> d_out (fp32)
        gemm_bt_kernel<1><<<dim3(kD / 256, kS / 256, kCB), 512, 0, stream>>>(
            SP, lagsT + off, out + off, nullptr, nullptr, lags + off, nullptr,
            kD, kS, (long long)kS * kS, (long long)kD * kS,
            (long long)kS * kD, (long long)kS * kD, 1.0f);
        // xb = bf16(LN1(x_pre))
        layernorm_kernel<<<kCB * kS, 256, 0, stream>>>(out + off, g1, be1, nullptr, xb + off);
    }

    // ---- FFN, kFR=16384 rows at a time (h spans lagsT+SP, both dead) ----
    for (int c = 0; c < (kB * kS) / kFR; c++) {
        const size_t roff = (size_t)c * kFR * kD;
        // h = bf16(gelu(x @ W1 + b1))
        gemm_bt_kernel<2><<<dim3(kE2 / 256, kFR / 256, 1), 512, 0, stream>>>(
            xb + roff, W1T, nullptr, h, b1, nullptr, nullptr,
            kE2, kD, 0, 0, 0, 0, 1.0f);
        // y = h @ W2 + b2 + x    -> d_out (fp32)
        gemm_bt_kernel<3><<<dim3(kD / 256, kFR / 256, 1), 512, 0, stream>>>(
            h, W2T, out + roff, nullptr, b2, nullptr, xb + roff,
            kD, kE2, 0, 0, 0, 0, 1.0f);
    }

    // ---- out = LN2(y), in place ----
    layernorm_kernel<<<kB * kS, 256, 0, stream>>>(out, g3, be3, out, nullptr);
}

// Round 7
// 1349.009 us; speedup vs baseline: 1.0833x; 1.0833x over previous
//
#include <hip/hip_runtime.h>
#include <hip/hip_bf16.h>
#include <cmath>

// SeqAttention: B=16, S=2048, D=1024, E2=4096.
// R7 = R5's measured-best K-loop (vmcnt(4) per K-tile, peeled tail, XCD
// swizzle, chunk XOR-swizzle, 0 bank conflicts) + NEW LDS-transposed
// coalesced epilogue:
//   old: 128 scalar stores/thread (32B segments, partial-line RMW ->
//        FFN1 WRITE 335MB vs 134MB ideal, FETCH amplified too).
//   new: per m-frag, stage 32x256 fp32 in LDS (row stride 260 -> 2-way max
//        write conflict = free), then each wave stores one contiguous 1KiB
//        (fp32) / 512B (bf16) row segment. Bias/residual/GELU applied at
//        read-back with coalesced float4/bf16x4 loads.

typedef __bf16 bf16;
typedef __attribute__((ext_vector_type(8))) __bf16 bf16x8;
typedef __attribute__((ext_vector_type(4))) __bf16 bf16x4;
typedef __attribute__((ext_vector_type(4))) float f32x4;

static constexpr int kB  = 16;
static constexpr int kS  = 2048;
static constexpr int kD  = 1024;
static constexpr int kE2 = 4096;
static constexpr int kCB = 8;      // batches per attention chunk (scores = 64MB)
static constexpr int kFR = 16384;  // rows per FFN super-chunk (h = 128MB)

// async global->LDS, 16 bytes per lane; LDS dest wave-uniform base + lane*16.
__device__ __forceinline__ void gload_lds16(const bf16* g, bf16* l) {
    __builtin_amdgcn_global_load_lds(
        (const __attribute__((address_space(1))) void*)g,
        (__attribute__((address_space(3))) void*)l,
        16, 0, 0);
}

__device__ __forceinline__ float gelu_exact(float t) {
    return 0.5f * t * (1.0f + erff(t * 0.70710678118654752f));
}

// ---------------- fp32 -> bf16 elementwise (4 elems/thread) ----------------
__global__ __launch_bounds__(256) void cvt_bf16_kernel(const float* __restrict__ in,
                                                       bf16* __restrict__ out) {
    size_t i = ((size_t)blockIdx.x * 256 + threadIdx.x) * 4;
    float4 v = *(const float4*)(in + i);
    bf16x4 o;
    o.x = (bf16)v.x; o.y = (bf16)v.y; o.z = (bf16)v.z; o.w = (bf16)v.w;
    *(bf16x4*)(out + i) = o;
}

// ---------------- tiled transpose + convert: out[c][r] = bf16(in[r][c]) ----
__global__ void transpose_cvt_kernel(const float* __restrict__ in, bf16* __restrict__ out,
                                     int R, int C, long long sIn, long long sOut) {
    __shared__ float tile[32][33];
    in  += (size_t)blockIdx.z * sIn;
    out += (size_t)blockIdx.z * sOut;
    const int c0 = blockIdx.x * 32, r0 = blockIdx.y * 32;
    const int tx = threadIdx.x, ty = threadIdx.y;
#pragma unroll
    for (int k = 0; k < 32; k += 8)
        tile[ty + k][tx] = in[(size_t)(r0 + ty + k) * C + (c0 + tx)];
    __syncthreads();
#pragma unroll
    for (int k = 0; k < 32; k += 8)
        out[(size_t)(c0 + ty + k) * R + (r0 + tx)] = (bf16)tile[tx][ty + k];
}

// ---------------- GEMM: C(MxN) = A(MxK) . B^T, B given as (NxK) -----------
// 256x256 tile, BK=64 as two 32-K halves. 8 waves 2x4; per-wave 128x64 out.
// LDS [buf][mat][khalf][256*32] = 128 KiB. Chunk XOR-swizzle (R3-verified,
// 0 conflicts): stage source chunk (lane&3)^((lane>>3)&3), read chunk
// quad^((l15>>1)&3). Stage map (iter i, phases 0..7 stage halves 8i+6..13):
//   p0: t=2i+1 A-kh1 b1   p1: t=2i+1 B-kh1 b1
//   p2: t=2i+2 A-kh0 b0   p3: t=2i+2 B-kh0 b0  + vmcnt(4)
//   p4: t=2i+2 A-kh1 b0   p5: t=2i+2 B-kh1 b0
//   p6: t=2i+3 A-kh0 b1   p7: t=2i+3 B-kh0 b1  + vmcnt(4)
// Peeled last iteration: p0/p1 stage final halves; vmcnt(0) at its p3.
// MODE 0: Cb = bf16(acc*scale)                (attention scores)
// MODE 1: C  = acc + resF                     (attn_out + residual, fp32)
// MODE 2: Cb = bf16(gelu_exact(acc + bias))   (FFN1 -> h)
// MODE 3: C  = acc + bias + resB              (FFN2 + residual, fp32)
template <int MODE>
__global__ __launch_bounds__(512, 2)
void gemm_bt_kernel(const bf16* __restrict__ A, const bf16* __restrict__ Bm,
                    float* __restrict__ C, bf16* __restrict__ Cb,
                    const float* __restrict__ bias,
                    const float* __restrict__ resF, const bf16* __restrict__ resB,
                    int N, int K,
                    long long sA, long long sB, long long sC, long long sRes,
                    float scale) {
    __shared__ __align__(16) bf16 lds[2][2][2][256 * 32];
    bf16* Lb = &lds[0][0][0][0];
    const int tid  = threadIdx.x;
    const int lane = tid & 63;
    const int wv   = tid >> 6;          // 0..7
    const int wm   = wv >> 2;           // 0..1  M-half
    const int wn   = wv & 3;            // 0..3  N-quarter
    const int quad = lane >> 4, l15 = lane & 15;
    const int quadS = quad ^ ((l15 >> 1) & 3);   // read-side chunk swizzle

    // ---- XCD-aware bijective block swizzle (grids are multiples of 8) ----
    const unsigned gx = gridDim.x, gy = gridDim.y;
    unsigned lin = blockIdx.x + gx * (blockIdx.y + gy * blockIdx.z);
    const unsigned nper = (gx * gy * gridDim.z) >> 3;
    lin = (lin & 7) * nper + (lin >> 3);
    const unsigned bx = lin % gx;
    const unsigned tq = lin / gx;
    const unsigned by = tq % gy;
    const long long z = tq / gy;

    const bf16* Ab = A  + z * sA + (size_t)by * 256 * K;
    const bf16* Bb = Bm + z * sB + (size_t)bx * 256 * K;

    // staging source (per lane): row wv*32 + lane>>2 (+16 for 2nd issue),
    // chunk pre-swizzled in the GLOBAL source (rule #21; LDS write linear).
    const int srow = wv * 32 + (lane >> 2);
    const int scol = ((lane & 3) ^ ((lane >> 3) & 3)) * 8;
    const bf16* gA = Ab + (size_t)srow * K + scol;
    const bf16* gB = Bb + (size_t)srow * K + scol;
    const size_t kk16 = (size_t)16 * K;
    const int NTH = K >> 7;             // K-tile pairs; K in {1024, 2048}

    // hoisted frag read bases (elem offsets; per-phase adds are constants)
    const bf16* aP = Lb + ((wm * 128 + l15) * 32 + quadS * 8);
    const bf16* bP = Lb + 16384 + ((wn * 64 + l15) * 32 + quadS * 8);
    bf16* ldsW = Lb + wv * 1024;        // staging dest base (32 rows)

    f32x4 acc[8][4];
#pragma unroll
    for (int i = 0; i < 8; i++)
#pragma unroll
        for (int j = 0; j < 4; j++) {
            f32x4 zv = {0.0f, 0.0f, 0.0f, 0.0f};
            acc[i][j] = zv;
        }

#define STG(GT, SEL, BUF)                                                     \
    do {                                                                      \
        const bf16* g_ = (((SEL) & 1) ? (GT##B) : (GT##A)) + ((SEL) >> 1) * 32; \
        bf16* l_ = ldsW + (BUF) * 32768 + ((SEL) & 1) * 16384 + ((SEL) >> 1) * 8192; \
        gload_lds16(g_, l_);                                                  \
        gload_lds16(g_ + kk16, l_ + 512);                                     \
    } while (0)

#define VMC4 asm volatile("s_waitcnt vmcnt(4)" ::: "memory")
#define VMC0 asm volatile("s_waitcnt vmcnt(0)" ::: "memory")

#define GPHASE(BUF, KS, QM, READB, STG_STMT, WAIT_STMT)                       \
    do {                                                                      \
        if (READB) {                                                          \
            _Pragma("unroll")                                                 \
            for (int nf = 0; nf < 4; nf++)                                    \
                bfr[nf] = *(const bf16x8*)(bP + (BUF) * 32768 + (KS) * 8192 + nf * 512); \
        }                                                                     \
        _Pragma("unroll")                                                     \
        for (int mf = 0; mf < 4; mf++)                                        \
            afr[mf] = *(const bf16x8*)(aP + (BUF) * 32768 + (KS) * 8192 + ((QM) * 4 + mf) * 512); \
        STG_STMT;                                                             \
        asm volatile("" ::: "memory");                                        \
        __builtin_amdgcn_s_barrier();                                         \
        asm volatile("s_waitcnt lgkmcnt(0)" ::: "memory");                    \
        __builtin_amdgcn_sched_barrier(0);                                    \
        __builtin_amdgcn_s_setprio(1);                                        \
        _Pragma("unroll")                                                     \
        for (int mf = 0; mf < 4; mf++)                                        \
            _Pragma("unroll")                                                 \
            for (int nf = 0; nf < 4; nf++)                                    \
                acc[(QM) * 4 + mf][nf] = __builtin_amdgcn_mfma_f32_16x16x32_bf16( \
                    afr[mf], bfr[nf], acc[(QM) * 4 + mf][nf], 0, 0, 0);       \
        __builtin_amdgcn_s_setprio(0);                                        \
        WAIT_STMT;                                                            \
        __builtin_amdgcn_s_barrier();                                        \
        asm volatile("" ::: "memory");                                        \
    } while (0)

    bf16x8 afr[4], bfr[4];
    {   // prologue: tile0 all 4 halves (buf0) + tile1 A/B-kh0 (buf1)
        const bf16* t0A = gA;      const bf16* t0B = gB;
        const bf16* t1A = gA + 64; const bf16* t1B = gB + 64;
        STG(t0, 0, 0); STG(t0, 1, 0); STG(t0, 2, 0); STG(t0, 3, 0);
        STG(t1, 0, 1); STG(t1, 1, 1);
        VMC4;                       // halves 0-3 landed (tile 0 complete)
        __builtin_amdgcn_s_barrier();
        asm volatile("" ::: "memory");
    }

    for (int i = 0; i < NTH - 1; i++) {
        const bf16* t1A = gA + (size_t)(2 * i + 1) * 64;
        const bf16* t1B = gB + (size_t)(2 * i + 1) * 64;
        const bf16* t2A = t1A + 64;  const bf16* t2B = t1B + 64;
        const bf16* t3A = t1A + 128; const bf16* t3B = t1B + 128;
        GPHASE(0, 0, 0, true,  STG(t1, 2, 1), (void)0);
        GPHASE(0, 0, 1, false, STG(t1, 3, 1), (void)0);
        GPHASE(0, 1, 0, true,  STG(t2, 0, 0), (void)0);
        GPHASE(0, 1, 1, false, STG(t2, 1, 0), VMC4);
        GPHASE(1, 0, 0, true,  STG(t2, 2, 0), (void)0);
        GPHASE(1, 0, 1, false, STG(t2, 3, 0), (void)0);
        GPHASE(1, 1, 0, true,  STG(t3, 0, 1), (void)0);
        GPHASE(1, 1, 1, false, STG(t3, 1, 1), VMC4);
    }
    {   // peeled last iteration: stage final two halves, then drain
        const int i = NTH - 1;
        const bf16* t1A = gA + (size_t)(2 * i + 1) * 64;
        const bf16* t1B = gB + (size_t)(2 * i + 1) * 64;
        GPHASE(0, 0, 0, true,  STG(t1, 2, 1), (void)0);
        GPHASE(0, 0, 1, false, STG(t1, 3, 1), (void)0);
        GPHASE(0, 1, 0, true,  (void)0, (void)0);
        GPHASE(0, 1, 1, false, (void)0, VMC0);
        GPHASE(1, 0, 0, true,  (void)0, (void)0);
        GPHASE(1, 0, 1, false, (void)0, (void)0);
        GPHASE(1, 1, 0, true,  (void)0, (void)0);
        GPHASE(1, 1, 1, false, (void)0, (void)0);
    }
#undef GPHASE
#undef STG
#undef VMC4
#undef VMC0

    // ---- epilogue v2: LDS-transposed coalesced C-write ----
    // Per m-frag: stage the block's 32x256 fp32 sub-tile in LDS (row stride
    // 260 floats -> write bank = (4*row+col)%32 -> 2-way max, free), then
    // wave wv stores padded row lr = s*8+wv as ONE contiguous wave store
    // (64 lanes x 16B). Mapping (verified): LDS[wm*16+quad*4+rr]
    // [wn*64+nf*16+l15] == C[by*256 + wm*128 + mf*16 + quad*4+rr]
    // [bx*256 + wn*64 + nf*16 + l15].
    float* eL = (float*)Lb;                               // 32 x 260 fp32
    float* eW = eL + (wm * 16 + quad * 4) * 260 + wn * 64 + l15;
    const size_t gcol = (size_t)bx * 256 + lane * 4;
    float4 b4;
    if (MODE == 2 || MODE == 3) b4 = *(const float4*)(bias + gcol);
    else { b4.x = 0.0f; b4.y = 0.0f; b4.z = 0.0f; b4.w = 0.0f; }

#pragma unroll
    for (int mf = 0; mf < 8; mf++) {
#pragma unroll
        for (int nf = 0; nf < 4; nf++)
#pragma unroll
            for (int rr = 0; rr < 4; rr++)
                eW[rr * 260 + nf * 16] = acc[mf][nf][rr];
        __syncthreads();
#pragma unroll
        for (int s = 0; s < 4; s++) {
            const int lr = s * 8 + wv;
            float4 v = *(const float4*)(eL + lr * 260 + lane * 4);
            const size_t row = (size_t)by * 256 + (size_t)(lr >> 4) * 128
                             + mf * 16 + (lr & 15);
            if (MODE == 0) {
                bf16x4 o;
                o.x = (bf16)(v.x * scale); o.y = (bf16)(v.y * scale);
                o.z = (bf16)(v.z * scale); o.w = (bf16)(v.w * scale);
                *(bf16x4*)(Cb + z * sC + row * N + gcol) = o;
            } else if (MODE == 1) {
                const float4 r4 = *(const float4*)(resF + z * sRes + row * N + gcol);
                float4 o;
                o.x = v.x + r4.x; o.y = v.y + r4.y;
                o.z = v.z + r4.z; o.w = v.w + r4.w;
                *(float4*)(C + z * sC + row * N + gcol) = o;
            } else if (MODE == 2) {
                bf16x4 o;
                o.x = (bf16)gelu_exact(v.x + b4.x);
                o.y = (bf16)gelu_exact(v.y + b4.y);
                o.z = (bf16)gelu_exact(v.z + b4.z);
                o.w = (bf16)gelu_exact(v.w + b4.w);
                *(bf16x4*)(Cb + row * N + gcol) = o;
            } else {
                const bf16x4 rb = *(const bf16x4*)(resB + row * N + gcol);
                float4 o;
                o.x = v.x + b4.x + (float)rb.x;
                o.y = v.y + b4.y + (float)rb.y;
                o.z = v.z + b4.z + (float)rb.z;
                o.w = v.w + b4.w + (float)rb.w;
                *(float4*)(C + row * N + gcol) = o;
            }
        }
        __syncthreads();
    }
}

// ---------------- row softmax over T=2048, bf16 in-place -------------------
__global__ __launch_bounds__(256)
void softmax_bf16_kernel(bf16* __restrict__ SP) {
    __shared__ float red[8];
    const size_t row = blockIdx.x;
    bf16* p = SP + row * kS;
    const int tid = threadIdx.x;
    bf16x8 v = *(const bf16x8*)(p + tid * 8);
    float f[8];
#pragma unroll
    for (int i = 0; i < 8; i++) f[i] = (float)v[i];
    float m = f[0];
#pragma unroll
    for (int i = 1; i < 8; i++) m = fmaxf(m, f[i]);
#pragma unroll
    for (int o = 32; o > 0; o >>= 1) m = fmaxf(m, __shfl_down(m, o, 64));
    if ((tid & 63) == 0) red[tid >> 6] = m;
    __syncthreads();
    m = fmaxf(fmaxf(red[0], red[1]), fmaxf(red[2], red[3]));
    float e[8], s = 0.0f;
#pragma unroll
    for (int i = 0; i < 8; i++) { e[i] = __expf(f[i] - m); s += e[i]; }
#pragma unroll
    for (int o = 32; o > 0; o >>= 1) s += __shfl_down(s, o, 64);
    __syncthreads();
    if ((tid & 63) == 0) red[4 + (tid >> 6)] = s;
    __syncthreads();
    s = red[4] + red[5] + red[6] + red[7];
    const float inv = 1.0f / s;
    bf16x8 o;
#pragma unroll
    for (int i = 0; i < 8; i++) o[i] = (bf16)(e[i] * inv);
    *(bf16x8*)(p + tid * 8) = o;
}

// ---------------- row LayerNorm over D=1024 (fp32 in), fp32/bf16 out -------
__global__ __launch_bounds__(256)
void layernorm_kernel(const float* __restrict__ in, const float* __restrict__ g,
                      const float* __restrict__ be, float* __restrict__ outF,
                      bf16* __restrict__ outB) {
    __shared__ float red[8];
    const size_t row = blockIdx.x;
    const float* src = in + row * kD;
    const int tid = threadIdx.x;
    float4 v = *(const float4*)(src + tid * 4);
    float s = v.x + v.y + v.z + v.w;
#pragma unroll
    for (int o = 32; o > 0; o >>= 1) s += __shfl_down(s, o, 64);
    if ((tid & 63) == 0) red[tid >> 6] = s;
    __syncthreads();
    const float mu = (red[0] + red[1] + red[2] + red[3]) * (1.0f / kD);
    const float d0 = v.x - mu, d1 = v.y - mu, d2 = v.z - mu, d3 = v.w - mu;
    float ss = d0 * d0 + d1 * d1 + d2 * d2 + d3 * d3;
#pragma unroll
    for (int o = 32; o > 0; o >>= 1) ss += __shfl_down(ss, o, 64);
    __syncthreads();
    if ((tid & 63) == 0) red[4 + (tid >> 6)] = ss;
    __syncthreads();
    const float var = (red[4] + red[5] + red[6] + red[7]) * (1.0f / kD);
    const float rstd = rsqrtf(var + 1e-5f);
    float4 gg = *(const float4*)(g + tid * 4);
    float4 bb = *(const float4*)(be + tid * 4);
    float4 o;
    o.x = d0 * rstd * gg.x + bb.x;
    o.y = d1 * rstd * gg.y + bb.y;
    o.z = d2 * rstd * gg.z + bb.z;
    o.w = d3 * rstd * gg.w + bb.w;
    if (outF) *(float4*)(outF + row * kD + tid * 4) = o;
    if (outB) {
        bf16x4 ob;
        ob.x = (bf16)o.x; ob.y = (bf16)o.y; ob.z = (bf16)o.z; ob.w = (bf16)o.w;
        *(bf16x4*)(outB + row * kD + tid * 4) = ob;
    }
}

extern "C" void kernel_launch(void* const* d_in, const int* in_sizes, int n_in,
                              void* d_out, int out_size, void* d_ws, size_t ws_size,
                              hipStream_t stream) {
    const float* lags = (const float*)d_in[0];
    const float* W1   = (const float*)d_in[1];
    const float* b1   = (const float*)d_in[2];
    const float* W2   = (const float*)d_in[3];
    const float* b2   = (const float*)d_in[4];
    const float* g1   = (const float*)d_in[5];
    const float* be1  = (const float*)d_in[6];
    const float* g3   = (const float*)d_in[7];
    const float* be3  = (const float*)d_in[8];
    float* out = (float*)d_out;   // also used as fp32 scratch (x_pre, then y)

    // ---- workspace carve-up: 208 MiB total ----
    // lagsb  bf16 [16][2048][1024]   64 MiB  @0    (QK^T operands; REUSED as xb)
    // W1T    bf16 [4096][1024]        8 MiB  @64M
    // W2T    bf16 [1024][4096]        8 MiB  @72M
    // lagsT  bf16 [16][1024][2048]   64 MiB  @80M  (V^T; DEAD after attention)
    // SP     bf16 [8][2048][2048]    64 MiB  @144M (scores/probs per chunk)
    // h = lagsT..SP = [16384][4096] bf16 = 128 MiB contiguous (FFN phase)
    const size_t REQUIRED = (size_t)(64 + 8 + 8 + 64 + 64) * 1024 * 1024;
    if (ws_size < REQUIRED) return;

    char* w = (char*)d_ws;
    bf16* lagsb = (bf16*)w; w += (size_t)kB * kS * kD * 2;
    bf16* W1T   = (bf16*)w; w += (size_t)kD * kE2 * 2;
    bf16* W2T   = (bf16*)w; w += (size_t)kE2 * kD * 2;
    bf16* lagsT = (bf16*)w; w += (size_t)kB * kD * kS * 2;
    bf16* SP    = (bf16*)w;
    bf16* xb    = lagsb;
    bf16* h     = lagsT;    // spans lagsT + SP (128 MiB)

    const int n = kB * kS * kD;

    // ---- operand prep ----
    cvt_bf16_kernel<<<n / 1024, 256, 0, stream>>>(lags, lagsb);
    transpose_cvt_kernel<<<dim3(kD / 32, kS / 32, kB), dim3(32, 8), 0, stream>>>(
        lags, lagsT, kS, kD, (long long)kS * kD, (long long)kD * kS);
    transpose_cvt_kernel<<<dim3(kE2 / 32, kD / 32, 1), dim3(32, 8), 0, stream>>>(
        W1, W1T, kD, kE2, 0, 0);
    transpose_cvt_kernel<<<dim3(kD / 32, kE2 / 32, 1), dim3(32, 8), 0, stream>>>(
        W2, W2T, kE2, kD, 0, 0);

    // ---- attention, kCB batches at a time ----
    for (int c = 0; c < kB / kCB; c++) {
        const size_t off = (size_t)c * kCB * kS * kD;
        // scores = bf16((lags @ lags^T) / 32)
        gemm_bt_kernel<0><<<dim3(kS / 256, kS / 256, kCB), 512, 0, stream>>>(
            lagsb + off, lagsb + off, nullptr, SP, nullptr, nullptr, nullptr,
            kS, kD, (long long)kS * kD, (long long)kS * kD, (long long)kS * kS, 0, 0.03125f);
        // P = softmax(scores), in place
        softmax_bf16_kernel<<<kCB * kS, 256, 0, stream>>>(SP);
        // x_pre = P @ V + lags   -> d_out (fp32)
        gemm_bt_kernel<1><<<dim3(kD / 256, kS / 256, kCB), 512, 0, stream>>>(
            SP, lagsT + off, out + off, nullptr, nullptr, lags + off, nullptr,
            kD, kS, (long long)kS * kS, (long long)kD * kS,
            (long long)kS * kD, (long long)kS * kD, 1.0f);
        // xb = bf16(LN1(x_pre))
        layernorm_kernel<<<kCB * kS, 256, 0, stream>>>(out + off, g1, be1, nullptr, xb + off);
    }

    // ---- FFN, kFR=16384 rows at a time (h spans lagsT+SP, both dead) ----
    for (int c = 0; c < (kB * kS) / kFR; c++) {
        const size_t roff = (size_t)c * kFR * kD;
        // h = bf16(gelu(x @ W1 + b1))
        gemm_bt_kernel<2><<<dim3(kE2 / 256, kFR / 256, 1), 512, 0, stream>>>(
            xb + roff, W1T, nullptr, h, b1, nullptr, nullptr,
            kE2, kD, 0, 0, 0, 0, 1.0f);
        // y = h @ W2 + b2 + x    -> d_out (fp32)
        gemm_bt_kernel<3><<<dim3(kD / 256, kFR / 256, 1), 512, 0, stream>>>(
            h, W2T, out + roff, nullptr, b2, nullptr, xb + roff,
            kD, kE2, 0, 0, 0, 0, 1.0f);
    }

    // ---- out = LN2(y), in place ----
    layernorm_kernel<<<kB * kS, 256, 0, stream>>>(out, g3, be3, out, nullptr);
}